// Round 2
// baseline (854.039 us; speedup 1.0000x reference)
//
#include <hip/hip_runtime.h>

// Problem constants (from reference setup_inputs)
#define FDIM 500
#define H1DIM 128
#define H2DIM 64
#define CDIM 10

using f32x4 = __attribute__((ext_vector_type(4))) float;
using bf16x8 = __attribute__((ext_vector_type(8))) short;  // 8 bf16 in 4 VGPRs

__device__ __forceinline__ unsigned short f32_to_bf16(float f) {
    unsigned u = __builtin_bit_cast(unsigned, f);
    u += 0x7FFFu + ((u >> 16) & 1u);  // RNE (inputs are finite, no NaN handling)
    return (unsigned short)(u >> 16);
}
__device__ __forceinline__ float bf16_to_f32(unsigned short h) {
    return __builtin_bit_cast(float, (unsigned)h << 16);
}
__device__ __forceinline__ float blo(unsigned u) {
    return __builtin_bit_cast(float, u << 16);
}
__device__ __forceinline__ float bhi(unsigned u) {
    return __builtin_bit_cast(float, u & 0xFFFF0000u);
}

// ---------------------------------------------------------------------------
// CSR build: histogram -> two-level scan -> atomic-cursor fill. dis = rsqrt(deg+1).
// fill also precomputes per-edge weight: ew[pos] = {src, dis[src]*dis[dst]}.
// ---------------------------------------------------------------------------

__global__ __launch_bounds__(256) void hist_kernel(const int* __restrict__ dst,
                                                   int* __restrict__ cnt, int E) {
    int e = blockIdx.x * 256 + threadIdx.x;
    if (e < E) atomicAdd(&cnt[dst[e]], 1);
}

__global__ __launch_bounds__(256) void dis_kernel(const int* __restrict__ cnt,
                                                  float* __restrict__ dis, int n) {
    int i = blockIdx.x * 256 + threadIdx.x;
    if (i < n) dis[i] = rsqrtf((float)cnt[i] + 1.0f);  // +1 self loop
}

__global__ __launch_bounds__(256) void block_reduce_kernel(const int* __restrict__ cnt,
                                                           int* __restrict__ bsums, int n) {
    __shared__ int s[256];
    int i = blockIdx.x * 256 + threadIdx.x;
    s[threadIdx.x] = (i < n) ? cnt[i] : 0;
    __syncthreads();
    for (int o = 128; o > 0; o >>= 1) {
        if (threadIdx.x < o) s[threadIdx.x] += s[threadIdx.x + o];
        __syncthreads();
    }
    if (threadIdx.x == 0) bsums[blockIdx.x] = s[0];
}

__global__ __launch_bounds__(512) void scan_sums_kernel(int* __restrict__ bsums, int nb,
                                                        int* __restrict__ row_ptr, int n) {
    __shared__ int s[512];
    int v = (threadIdx.x < nb) ? bsums[threadIdx.x] : 0;
    s[threadIdx.x] = v;
    __syncthreads();
    for (int o = 1; o < 512; o <<= 1) {
        int t = (threadIdx.x >= o) ? s[threadIdx.x - o] : 0;
        __syncthreads();
        s[threadIdx.x] += t;
        __syncthreads();
    }
    if (threadIdx.x < nb) bsums[threadIdx.x] = s[threadIdx.x] - v;  // exclusive
    if (threadIdx.x == 511) row_ptr[n] = s[511];                    // total == E
}

__global__ __launch_bounds__(256) void scan_blocks_kernel(const int* __restrict__ cnt,
                                                          const int* __restrict__ bsums,
                                                          int* __restrict__ row_ptr,
                                                          int* __restrict__ cursor, int n) {
    __shared__ int s[256];
    int i = blockIdx.x * 256 + threadIdx.x;
    int v = (i < n) ? cnt[i] : 0;
    s[threadIdx.x] = v;
    __syncthreads();
    for (int o = 1; o < 256; o <<= 1) {
        int t = (threadIdx.x >= o) ? s[threadIdx.x - o] : 0;
        __syncthreads();
        s[threadIdx.x] += t;
        __syncthreads();
    }
    int excl = s[threadIdx.x] - v + bsums[blockIdx.x];
    if (i < n) {
        row_ptr[i] = excl;
        cursor[i] = excl;
    }
}

__global__ __launch_bounds__(256) void fill_kernel(const int* __restrict__ src,
                                                   const int* __restrict__ dst,
                                                   const float* __restrict__ dis,
                                                   int* __restrict__ cursor,
                                                   int2* __restrict__ ew, int E) {
    int e = blockIdx.x * 256 + threadIdx.x;
    if (e < E) {
        int d = dst[e];
        int s = src[e];
        int pos = atomicAdd(&cursor[d], 1);
        float w = dis[s] * dis[d];
        ew[pos] = make_int2(s, __builtin_bit_cast(int, w));
    }
}

// ---------------------------------------------------------------------------
// Pre-pack W (fp32 [K,N]) into MFMA B-fragment layout, bf16, K zero-padded.
// ---------------------------------------------------------------------------
__global__ __launch_bounds__(256) void pack_w_kernel(const float* __restrict__ W,
                                                     unsigned short* __restrict__ Bp,
                                                     int K, int N, int T) {
    int idx = blockIdx.x * 256 + threadIdx.x;
    int NF = N >> 4;
    int total = T * NF * 64;
    if (idx >= total) return;
    int lane = idx & 63;
    int tnf = idx >> 6;
    int nf = tnf % NF;
    int t = tnf / NF;
    int kbase = t * 32 + (lane >> 4) * 8;
    int n = nf * 16 + (lane & 15);
    unsigned short v[8];
#pragma unroll
    for (int j = 0; j < 8; j++) {
        int k = kbase + j;
        float f = (k < K) ? W[(size_t)k * N + n] : 0.f;
        v[j] = f32_to_bf16(f);
    }
    uint4 p;
    p.x = (unsigned)v[0] | ((unsigned)v[1] << 16);
    p.y = (unsigned)v[2] | ((unsigned)v[3] << 16);
    p.z = (unsigned)v[4] | ((unsigned)v[5] << 16);
    p.w = (unsigned)v[6] | ((unsigned)v[7] << 16);
    *(uint4*)(Bp + (size_t)idx * 8) = p;
}

// ---------------------------------------------------------------------------
// LDS-free MFMA GEMM v2: 64 rows per wave (4 m-frags) -> 2x register B-reuse.
// CHUNKED epilogue writes C in 16-channel chunk-major slices
// (slice ch: [M rows x 16 ch] contiguous) so the aggregation pass can keep one
// 3.2 MB slice L2-resident per XCD. Same per-instruction write coalescing.
// ---------------------------------------------------------------------------
template <int NB, int K, bool ABF16, bool CHUNKED>
__global__ __launch_bounds__(64) void gemm_mfma(const void* __restrict__ Avoid,
                                                const unsigned short* __restrict__ Bp,
                                                unsigned short* __restrict__ C, int M) {
    constexpr int NF = NB / 16;
    constexpr int FULL = K / 32;
    constexpr int REM = K % 32;
    const int lane = threadIdx.x;
    const int quad = lane >> 4;
    const int mrow = lane & 15;
    const int m_base = blockIdx.x * 64;

    f32x4 acc[4][NF];
#pragma unroll
    for (int i = 0; i < 4; i++)
#pragma unroll
        for (int j = 0; j < NF; j++) acc[i][j] = (f32x4)(0.f);

    int c[4];
#pragma unroll
    for (int i = 0; i < 4; i++) c[i] = min(m_base + i * 16 + mrow, M - 1);  // stores guarded

    const float* Af = (const float*)Avoid;
    const unsigned short* Ah = (const unsigned short*)Avoid;

    for (int t = 0; t < FULL; t++) {
        const int k0 = t * 32 + quad * 8;
        bf16x8 a[4];
        if (ABF16) {
#pragma unroll
            for (int i = 0; i < 4; i++)
                a[i] = *(const bf16x8*)(Ah + (size_t)c[i] * K + k0);
        } else {
#pragma unroll
            for (int i = 0; i < 4; i++) {
                const float* p = Af + (size_t)c[i] * K + k0;
                float4 x = *(const float4*)p, y = *(const float4*)(p + 4);
                a[i][0] = (short)f32_to_bf16(x.x); a[i][1] = (short)f32_to_bf16(x.y);
                a[i][2] = (short)f32_to_bf16(x.z); a[i][3] = (short)f32_to_bf16(x.w);
                a[i][4] = (short)f32_to_bf16(y.x); a[i][5] = (short)f32_to_bf16(y.y);
                a[i][6] = (short)f32_to_bf16(y.z); a[i][7] = (short)f32_to_bf16(y.w);
            }
        }
#pragma unroll
        for (int nf = 0; nf < NF; nf++) {
            bf16x8 b = *(const bf16x8*)(Bp + (size_t)(t * NF + nf) * 512 + lane * 8);
#pragma unroll
            for (int i = 0; i < 4; i++)
                acc[i][nf] = __builtin_amdgcn_mfma_f32_16x16x32_bf16(a[i], b, acc[i][nf], 0, 0, 0);
        }
    }
    if constexpr (REM > 0) {  // K tail: guarded element loads, B tile zero-padded
        const int kb = FULL * 32 + quad * 8;
        bf16x8 a[4];
#pragma unroll
        for (int i = 0; i < 4; i++) {
#pragma unroll
            for (int j = 0; j < 8; j++) {
                int k = kb + j;
                float v = 0.f;
                if (k < K)
                    v = ABF16 ? bf16_to_f32(Ah[(size_t)c[i] * K + k]) : Af[(size_t)c[i] * K + k];
                a[i][j] = (short)f32_to_bf16(v);
            }
        }
#pragma unroll
        for (int nf = 0; nf < NF; nf++) {
            bf16x8 b = *(const bf16x8*)(Bp + (size_t)(FULL * NF + nf) * 512 + lane * 8);
#pragma unroll
            for (int i = 0; i < 4; i++)
                acc[i][nf] = __builtin_amdgcn_mfma_f32_16x16x32_bf16(a[i], b, acc[i][nf], 0, 0, 0);
        }
    }

    // epilogue: within m-frag i, D row = quad*4 + ii, col = nf*16 + mrow
#pragma unroll
    for (int i = 0; i < 4; i++)
#pragma unroll
        for (int ii = 0; ii < 4; ii++) {
            const int r = m_base + i * 16 + quad * 4 + ii;
            if (r < M) {
#pragma unroll
                for (int nf = 0; nf < NF; nf++) {
                    const size_t idx = CHUNKED ? ((size_t)nf * M + r) * 16 + mrow
                                               : (size_t)r * NB + nf * 16 + mrow;
                    C[idx] = f32_to_bf16(acc[i][nf][ii]);
                }
            }
        }
}

// ---------------------------------------------------------------------------
// Chunked aggregation: the feature table is stored chunk-major in 16-channel
// slices (100k x 32B = 3.2 MB -> fits a 4 MB per-XCD L2). grid = (nodeblocks,
// NCH) with chunk the SLOW dim, so all concurrently-resident blocks work the
// same slice and every XCD keeps a full copy L2-resident: the random per-edge
// row gathers become L2 hits instead of L3/fabric round-trips.
// ew is streamed nontemporally (once per pass) to avoid evicting the slice.
// Wave layout: 2 nodes/wave; per node 8 edge-slots x 4 lanes (uint2 = 4 ch).
// Output written row-major (bf16 for layer 1 -> GEMM2 A; fp32 for layer 2).
// ---------------------------------------------------------------------------
template <int D, bool OUTBF16>
__global__ __launch_bounds__(256) void aggregate_chunked(const uint2* __restrict__ hc,
                                                         const float* __restrict__ dis,
                                                         const int* __restrict__ row_ptr,
                                                         const int2* __restrict__ ew,
                                                         const float* __restrict__ bias,
                                                         void* __restrict__ outv, int n) {
    const int lane = threadIdx.x & 63;
    const int wid = threadIdx.x >> 6;
    const int nsub = lane >> 5;         // node within wave
    const int eslot = (lane >> 2) & 7;  // edge slot (8 per node)
    const int cpos = lane & 3;          // uint2 within the 32B chunk row-slice
    const int node = (blockIdx.x * 4 + wid) * 2 + nsub;
    const bool active = node < n;
    const int nc = active ? node : n - 1;
    const int ch = blockIdx.y;
    const uint2* slice = hc + (size_t)ch * n * 4;  // chunk slice, uint2 units

    const float di = dis[nc];
    const int beg = row_ptr[nc];
    const int end = active ? row_ptr[nc + 1] : beg;

    float ax0, ax1, ax2, ax3;
    {
        uint2 v = slice[(size_t)nc * 4 + cpos];
        float ws = (eslot == 0) ? di * di : 0.f;  // self term counted once
        ax0 = ws * blo(v.x); ax1 = ws * bhi(v.x);
        ax2 = ws * blo(v.y); ax3 = ws * bhi(v.y);
    }
    for (int jb = beg; jb < end; jb += 8) {
        const int e = jb + eslot;
        const bool ok = e < end;  // eslot-uniform -> clean exec masking
        long long pe = __builtin_nontemporal_load((const long long*)ew + min(e, end - 1));
        const int s = (int)(unsigned)pe;
        const float w = ok ? __builtin_bit_cast(float, (int)(pe >> 32)) : 0.f;
        uint2 v = make_uint2(0u, 0u);
        if (ok) v = slice[(size_t)s * 4 + cpos];  // 4 lanes = contiguous 32B, L2-hit
        ax0 = fmaf(w, blo(v.x), ax0); ax1 = fmaf(w, bhi(v.x), ax1);
        ax2 = fmaf(w, blo(v.y), ax2); ax3 = fmaf(w, bhi(v.y), ax3);
    }
    // reduce across the 8 edge slots (lane bits 2..4, stays within each node half)
    ax0 += __shfl_xor(ax0, 4); ax0 += __shfl_xor(ax0, 8); ax0 += __shfl_xor(ax0, 16);
    ax1 += __shfl_xor(ax1, 4); ax1 += __shfl_xor(ax1, 8); ax1 += __shfl_xor(ax1, 16);
    ax2 += __shfl_xor(ax2, 4); ax2 += __shfl_xor(ax2, 8); ax2 += __shfl_xor(ax2, 16);
    ax3 += __shfl_xor(ax3, 4); ax3 += __shfl_xor(ax3, 8); ax3 += __shfl_xor(ax3, 16);
    if (eslot == 0 && active) {
        const float4 b = *(const float4*)(bias + ch * 16 + cpos * 4);
        const float r0 = fmaxf(ax0 + b.x, 0.f);
        const float r1 = fmaxf(ax1 + b.y, 0.f);
        const float r2 = fmaxf(ax2 + b.z, 0.f);
        const float r3 = fmaxf(ax3 + b.w, 0.f);
        if (OUTBF16) {
            uint2 r;
            r.x = (unsigned)f32_to_bf16(r0) | ((unsigned)f32_to_bf16(r1) << 16);
            r.y = (unsigned)f32_to_bf16(r2) | ((unsigned)f32_to_bf16(r3) << 16);
            ((uint2*)outv)[(size_t)node * (D / 4) + ch * 4 + cpos] = r;
        } else {
            float4 r;
            r.x = r0; r.y = r1; r.z = r2; r.w = r3;
            ((float4*)outv)[(size_t)node * (D / 4) + ch * 4 + cpos] = r;
        }
    }
}

// ---------------------------------------------------------------------------
// classifier: out[M x 10] = A[M x 64] * Wc[64 x 10] + bc. 16 threads/row.
// ---------------------------------------------------------------------------
__global__ __launch_bounds__(256) void classifier_kernel(const float* __restrict__ A,
                                                         const float* __restrict__ Wc,
                                                         const float* __restrict__ bc,
                                                         float* __restrict__ out, int M) {
    int idx = blockIdx.x * 256 + threadIdx.x;
    int row = idx >> 4;
    int c = idx & 15;
    if (row >= M || c >= CDIM) return;
    const float* a = A + (size_t)row * H2DIM;
    float acc = bc[c];
#pragma unroll 8
    for (int k = 0; k < H2DIM; k++) acc = fmaf(a[k], Wc[k * CDIM + c], acc);
    out[(size_t)row * CDIM + c] = acc;
}

// ---------------------------------------------------------------------------

extern "C" void kernel_launch(void* const* d_in, const int* in_sizes, int n_in,
                              void* d_out, int out_size, void* d_ws, size_t ws_size,
                              hipStream_t stream) {
    const float* x  = (const float*)d_in[0];
    const int*   ei = (const int*)d_in[1];
    const float* W1 = (const float*)d_in[2];
    const float* b1 = (const float*)d_in[3];
    const float* W2 = (const float*)d_in[4];
    const float* b2 = (const float*)d_in[5];
    const float* Wc = (const float*)d_in[6];
    const float* bc = (const float*)d_in[7];
    float* out = (float*)d_out;

    const int N = in_sizes[0] / FDIM;  // 100000
    const int E = in_sizes[1] / 2;     // 1600000
    const int* src = ei;
    const int* dst = ei + E;

    // workspace layout (bytes); agg2f overlays h1 (h1 dead after its aggregation)
    char* ws = (char*)d_ws;
    int*            cnt    = (int*)(ws + 0x000000);   // N ints (reused as cursor)
    int*            rowptr = (int*)(ws + 0x080000);   // N+1 ints
    float*          dis    = (float*)(ws + 0x100000); // N floats
    int*            bsums  = (int*)(ws + 0x180000);   // ceil(N/256) ints
    int2*           ew     = (int2*)(ws + 0x200000);  // E int2 (12.8 MB)
    unsigned short* W1p    = (unsigned short*)(ws + 0xE40000);  // 128 KB
    unsigned short* W2p    = (unsigned short*)(ws + 0xE80000);  // 16 KB
    unsigned short* h1     = (unsigned short*)(ws + 0xF00000);  // N*128 bf16, chunk-major (25.6 MB)
    float*          agg2f  = (float*)(ws + 0xF00000);           // N*64 fp32 (overlays h1)
    unsigned short* agg1   = (unsigned short*)(ws + 0x2800000); // N*128 bf16 row-major (25.6 MB)
    unsigned short* h2     = (unsigned short*)(ws + 0x4200000); // N*64 bf16, chunk-major (12.8 MB)

    const int nb = (N + 255) / 256;

    // 1. CSR build + dis + per-edge weights
    hipMemsetAsync(cnt, 0, (size_t)N * sizeof(int), stream);
    hist_kernel<<<(E + 255) / 256, 256, 0, stream>>>(dst, cnt, E);
    dis_kernel<<<nb, 256, 0, stream>>>(cnt, dis, N);
    block_reduce_kernel<<<nb, 256, 0, stream>>>(cnt, bsums, N);
    scan_sums_kernel<<<1, 512, 0, stream>>>(bsums, nb, rowptr, N);
    scan_blocks_kernel<<<nb, 256, 0, stream>>>(cnt, bsums, rowptr, /*cursor=*/cnt, N);
    fill_kernel<<<(E + 255) / 256, 256, 0, stream>>>(src, dst, dis, /*cursor=*/cnt, ew, E);

    // 2. pack weights to MFMA B-fragment bf16 layout
    pack_w_kernel<<<(16 * 8 * 64 + 255) / 256, 256, 0, stream>>>(W1, W1p, FDIM, H1DIM, 16);
    pack_w_kernel<<<(4 * 4 * 64 + 255) / 256, 256, 0, stream>>>(W2, W2p, H1DIM, H2DIM, 4);

    const int gblocks = (N + 63) / 64;        // GEMM: one wave / 64 rows
    const int ablocks = (N + 7) / 8;          // agg: 8 nodes / 256-thread block

    // 3. layer 1: GEMM writes h1 chunk-major; chunked agg -> agg1 row-major bf16
    gemm_mfma<H1DIM, FDIM, false, true><<<gblocks, 64, 0, stream>>>(x, W1p, h1, N);
    aggregate_chunked<H1DIM, true><<<dim3(ablocks, H1DIM / 16), 256, 0, stream>>>(
        (const uint2*)h1, dis, rowptr, ew, b1, agg1, N);

    // 4. layer 2: GEMM writes h2 chunk-major; chunked agg -> agg2f row-major fp32
    gemm_mfma<H2DIM, H1DIM, true, true><<<gblocks, 64, 0, stream>>>(agg1, W2p, h2, N);
    aggregate_chunked<H2DIM, false><<<dim3(ablocks, H2DIM / 16), 256, 0, stream>>>(
        (const uint2*)h2, dis, rowptr, ew, b2, agg2f, N);

    // 5. classifier
    classifier_kernel<<<(N * 16 + 255) / 256, 256, 0, stream>>>(agg2f, Wc, bc, out, N);
}